// Round 5
// baseline (372.402 us; speedup 1.0000x reference)
//
#include <hip/hip_runtime.h>

// Emission-absorption volume renderer. fp32 in/out (verified R4 diagnostic:
// inputs in insertion order dens,feats,lens,dirs; outputs fp32 flat
// [features(3NR) | depths(NR) | opac(NR) | weights(128NR)], NR=131072).
// One 64-lane wave per ray; lane l owns samples n=2l and n=2l+1.
//
// KEY NUMERICAL FIX vs R1/R3: the lane-63 sentinel delta (1e10) must NOT
// enter the prefix scan — at 2e10 the fp32 ulp is 2048, so excl = inc - s
// cancels catastrophically and absorption_shifted[126..127] comes out ~1
// instead of exp(-S_prev) (features error up to ~1, observed 1.0039).
// Reference semantics: absorption_shifted[127] = exp(-cumsum[126]) — the
// sentinel only ever feeds the final opacity, where exp(-2e10) == 0.

#define BG_OPACITY_F 1e10f

__global__ __launch_bounds__(256) void ea_render_kernel(
    const float* __restrict__ dens,    // (rays, 128)
    const float* __restrict__ feats,   // (rays, 128, 3)
    const float* __restrict__ lens,    // (rays, 128)
    const float* __restrict__ dirs,    // (rays, 3)
    float* __restrict__ out_feat,      // (rays, 3)
    float* __restrict__ out_depth,     // (rays)
    float* __restrict__ out_opac,      // (rays)
    float* __restrict__ out_w,         // (rays, 128)
    int n_rays)
{
    const int wave = threadIdx.x >> 6;               // 0..3
    const int lane = threadIdx.x & 63;
    const long ray = (long)blockIdx.x * 4 + wave;
    if (ray >= n_rays) return;

    const long base = ray * 128;
    const int n0 = lane * 2;

    // ---- coalesced loads (8 B / lane) ----
    const float2 d2 = *(const float2*)(dens + base + n0);   // densities n0, n0+1
    const float2 l2 = *(const float2*)(lens + base + n0);   // lengths   n0, n0+1

    // ray direction norm (12 B broadcast from cache)
    const float* dp = dirs + ray * 3;
    const float dx = dp[0], dy = dp[1], dz = dp[2];
    const float dn = sqrtf(dx * dx + dy * dy + dz * dz);

    // ---- deltas ----
    // delta[n] = len[n+1]-len[n], n<127 ; delta[127] = BG_OPACITY
    const float lnext = __shfl_down(l2.x, 1, 64);   // lane l <- lane l+1's len[2l+2]
    const float delta0 = l2.y - l2.x;
    const float delta1 = (lane == 63) ? BG_OPACITY_F : (lnext - l2.y);

    const float w0 = delta0 * dn * fmaxf(d2.x, 0.0f);
    const float w1 = delta1 * dn * fmaxf(d2.y, 0.0f);

    // ---- wave-wide inclusive scan of per-lane pair sums ----
    // Sentinel excluded: scanned values stay O(10), no cancellation.
    const float w1s = (lane == 63) ? 0.0f : w1;
    const float s = w0 + w1s;
    float inc = s;
    #pragma unroll
    for (int off = 1; off < 64; off <<= 1) {
        const float t = __shfl_up(inc, off, 64);
        if (lane >= off) inc += t;
    }
    const float excl = inc - s;        // sum of weighted over all n < 2l (exact-ish)

    // ---- weights ----
    const float e0 = __expf(-w0);
    const float e1 = __expf(-w1);      // lane 63: exp(-~2e10) = 0 (or 1 if dens==0)
    const float a0 = __expf(-excl);    // absorption_shifted at n0
    const float a1 = a0 * e0;          // absorption_shifted at n0+1
    const float wgt0 = (1.0f - e0) * a0;
    const float wgt1 = (1.0f - e1) * a1;

    // ---- opacity: re-add the sentinel term (reference cumsum[127]) ----
    const float total_real = __shfl(inc, 63, 64);   // sum of real weighted
    const float w1_last    = __shfl(w1, 63, 64);    // sentinel weighted term
    const float opac = 1.0f - __expf(-(total_real + w1_last));

    // ---- per-lane partials ----
    float pd = wgt0 * l2.x + wgt1 * l2.y;

    const float* fp = feats + base * 3 + (long)n0 * 3;      // 6 floats, 8B-aligned
    const float2 f01 = *(const float2*)(fp);
    const float2 f23 = *(const float2*)(fp + 2);
    const float2 f45 = *(const float2*)(fp + 4);
    // sample n0:   (f01.x, f01.y, f23.x)   sample n0+1: (f23.y, f45.x, f45.y)
    float fr = wgt0 * f01.x + wgt1 * f23.y;
    float fg = wgt0 * f01.y + wgt1 * f45.x;
    float fb = wgt0 * f23.x + wgt1 * f45.y;

    // ---- wave butterfly reductions (depth + 3 feature channels) ----
    #pragma unroll
    for (int off = 32; off; off >>= 1) {
        pd += __shfl_xor(pd, off, 64);
        fr += __shfl_xor(fr, off, 64);
        fg += __shfl_xor(fg, off, 64);
        fb += __shfl_xor(fb, off, 64);
    }

    // ---- stores ----
    *(float2*)(out_w + base + n0) = make_float2(wgt0, wgt1);   // coalesced

    if (lane == 0) {
        // features += (1 - opac) * BG_COLOR with BG_COLOR == 0 -> no-op
        out_feat[ray * 3 + 0] = fr;
        out_feat[ray * 3 + 1] = fg;
        out_feat[ray * 3 + 2] = fb;
        out_depth[ray] = pd;
        out_opac[ray] = opac;
    }
}

extern "C" void kernel_launch(void* const* d_in, const int* in_sizes, int n_in,
                              void* d_out, int out_size, void* d_ws, size_t ws_size,
                              hipStream_t stream) {
    // Input order verified (R4 decode): dens(0), feats(1), lens(2), dirs(3).
    const float* dens  = (const float*)d_in[0];  // (B,R,N,1)
    const float* feats = (const float*)d_in[1];  // (B,R,N,3)
    const float* lens  = (const float*)d_in[2];  // (B,R,N)
    const float* dirs  = (const float*)d_in[3];  // (B,R,3)

    const int n_rays = in_sizes[3] / 3;          // B*R = 131072

    float* out = (float*)d_out;
    float* out_feat  = out;                       // (rays, 3)
    float* out_depth = out + (long)n_rays * 3;    // (rays, 1)
    float* out_opac  = out + (long)n_rays * 4;    // (rays, 1)
    float* out_w     = out + (long)n_rays * 5;    // (rays, 128)

    const int blocks = (n_rays + 3) / 4;          // 4 rays (waves) per block
    ea_render_kernel<<<blocks, 256, 0, stream>>>(
        dens, feats, lens, dirs, out_feat, out_depth, out_opac, out_w, n_rays);
}